// Round 11
// baseline (1489.208 us; speedup 1.0000x reference)
//
#include <hip/hip_runtime.h>
#include <math.h>

#define BH 256
#define BW 256
#define NB 32
#define NC 32
#define TPB 256
#define NRED 1024      // reducer blocks
#define NROT 1024      // rotator blocks
#define NTOT (NRED + NROT)   // 2048 = 8 blocks/CU (coop-resident)
#define LAG  4         // back-pressure window (batches) -> ~32 MB L3 pollution cap
#define RB 64          // fallback-path reduction blocks per batch

typedef float nfloat4 __attribute__((ext_vector_type(4)));
#define AGENT __HIP_MEMORY_SCOPE_AGENT

// ===================== fused producer/consumer kernel ========================
// Blocks 0..1023: REDUCERS, batch-sequential. Blocks 1024..2047: ROTATORS,
// consuming the ready-batch queue. No stage lockstep -> no per-stage convoy
// (R10's 100us loss). Sync = relaxed agent atomics at L3 + completion ordering
// via s_waitcnt vmcnt(0) (NO acquire/release: gfx950 agent release = L2
// writeback storm, R8/R9 evidence). ready = one 32-bit mask word. Rotator r
// rotates the same slice reducer r streamed (same XCD mod 8 -> L2-warm).
// LAG back-pressure bounds reducer lead so gathers stay cache-hot.
__global__ __launch_bounds__(TPB, 8) void k_fused(
    const float* __restrict__ x, const float* __restrict__ Wm,
    const float* __restrict__ bias, float* __restrict__ out,
    float* __restrict__ partial,          // [NB][NRED]
    unsigned* __restrict__ cnt1,          // [NB][32]
    unsigned* __restrict__ cnt2,          // [NB]
    unsigned* __restrict__ rotc,          // [NB]
    unsigned* __restrict__ ready_mask,    // [1]
    float* __restrict__ params)           // [NB][4] = cc, sn, xoff, yoff
{
    const int k = blockIdx.x, t = threadIdx.x;
    const int lane = t & 63, wv = t >> 6;

    if (k < NRED) {
        // ------------------------------ REDUCER ------------------------------
        __shared__ float red[4];
        const int cb = (t * 4) & (NC - 1);       // k*2048 % 32 == 0 -> t-only
        const float w0 = Wm[cb], w1 = Wm[cb + 1], w2 = Wm[cb + 2], w3 = Wm[cb + 3];
        const float bias0 = bias[0];

        for (int b = 0; b < NB; ++b) {
            // back-pressure: stay <= LAG batches ahead of rotators
            if (b >= LAG && wv == 0 && lane == 0)
                while (__hip_atomic_load(&rotc[b - LAG], __ATOMIC_RELAXED, AGENT) < NROT)
                    __builtin_amdgcn_s_sleep(4);
            __syncthreads();                     // B0: poll done; red reusable
            const float4* xb4 = (const float4*)(x + (size_t)b * (BH * BW * NC));
            const int base = k * 512 + t;
            const float4 a0 = xb4[base];
            const float4 a1 = xb4[base + 256];
            float s = a0.x * w0 + a0.y * w1 + a0.z * w2 + a0.w * w3
                    + a1.x * w0 + a1.y * w1 + a1.z * w2 + a1.w * w3;
            #pragma unroll
            for (int off = 32; off; off >>= 1) s += __shfl_down(s, off, 64);
            if (lane == 0) red[wv] = s;
            __syncthreads();                     // B1
            if (wv == 0) {
                if (lane == 0) {
                    const float bsum = red[0] + red[1] + red[2] + red[3];
                    __hip_atomic_store(&partial[(size_t)b * NRED + k], bsum,
                                       __ATOMIC_RELAXED, AGENT);
                }
                asm volatile("s_waitcnt vmcnt(0)" ::: "memory");  // partial at L3
                int last = 0;
                if (lane == 0) {
                    const unsigned o1 = __hip_atomic_fetch_add(&cnt1[b * 32 + (k >> 5)],
                                                               1u, __ATOMIC_RELAXED, AGENT);
                    if (o1 == 31u) {
                        const unsigned o2 = __hip_atomic_fetch_add(&cnt2[b], 1u,
                                                                   __ATOMIC_RELAXED, AGENT);
                        last = (o2 == 31u);
                    }
                }
                last = __shfl(last, 0, 64);
                if (last) {  // finalize batch b: fixed-order sum -> deterministic
                    const float* pb = partial + (size_t)b * NRED;
                    float q = 0.f;
                    #pragma unroll
                    for (int i = 0; i < 16; ++i)
                        q += __hip_atomic_load(&pb[lane + 64 * i], __ATOMIC_RELAXED, AGENT);
                    #pragma unroll
                    for (int off = 32; off; off >>= 1) q += __shfl_down(q, off, 64);
                    if (lane == 0) {
                        const float pi = 3.14159265358979323846f;
                        float angle = tanhf(q * (1.f / (BH * BW)) + bias0) * pi;
                        angle = fminf(fmaxf(angle, -pi), pi);
                        const float c_ = cosf(angle), s_ = sinf(angle);
                        const float w1f = (float)(BW - 1), h1f = (float)(BH - 1);
                        __hip_atomic_store(&params[b * 4 + 0], c_, __ATOMIC_RELAXED, AGENT);
                        __hip_atomic_store(&params[b * 4 + 1], s_, __ATOMIC_RELAXED, AGENT);
                        __hip_atomic_store(&params[b * 4 + 2],
                                           (w1f - (c_ * w1f - s_ * h1f)) * 0.5f,
                                           __ATOMIC_RELAXED, AGENT);
                        __hip_atomic_store(&params[b * 4 + 3],
                                           (h1f - (s_ * w1f + c_ * h1f)) * 0.5f,
                                           __ATOMIC_RELAXED, AGENT);
                        asm volatile("s_waitcnt vmcnt(0)" ::: "memory"); // params at L3
                        __hip_atomic_fetch_or(ready_mask, 1u << b, __ATOMIC_RELAXED, AGENT);
                    }
                }
            }
        }
    } else {
        // ------------------------------ ROTATOR ------------------------------
        __shared__ float sprm[2][4];
        const int r = k - NRED;
        unsigned seen = 0u;
        for (int b = 0; b < NB; ++b) {
            if (wv == 0) {
                if (lane == 0 && !((seen >> b) & 1u)) {
                    unsigned m;
                    do {
                        m = __hip_atomic_load(ready_mask, __ATOMIC_RELAXED, AGENT);
                        if (!((m >> b) & 1u)) __builtin_amdgcn_s_sleep(2);
                    } while (!((m >> b) & 1u));
                    seen = m;
                }
                // wave lockstep: loads below issue only after lane0's poll exits
                if (lane < 4)
                    sprm[b & 1][lane] = __hip_atomic_load(&params[b * 4 + lane],
                                                          __ATOMIC_RELAXED, AGENT);
            }
            __syncthreads();                     // sprm[b&1] valid (parity-safe)
            const float cc = sprm[b & 1][0], sn = sprm[b & 1][1];
            const float xof = sprm[b & 1][2], yof = sprm[b & 1][3];
            const float* xb = x + (size_t)b * (BH * BW * NC);
            float* ob = out + (size_t)b * (BH * BW * NC);
            #pragma unroll
            for (int h = 0; h < 2; ++h) {
                const int j   = r * 512 + h * 256 + t;   // float4 index in batch
                const int c4  = (j & 7) * 4;
                const int pid = j >> 3;
                const int xo = pid & 255, yo = pid >> 8;
                const float fx = (float)xo, fy = (float)yo;
                const float in_x = cc * fx - sn * fy + xof;
                const float in_y = sn * fx + cc * fy + yof;
                const float x0 = floorf(in_x), y0 = floorf(in_y);
                const float wxf = in_x - x0, wyf = in_y - y0;
                const int x0i = (int)x0, y0i = (int)y0;
                auto pix = [&](int yi, int xi) -> float4 {
                    const bool valid = (xi >= 0) & (xi < BW) & (yi >= 0) & (yi < BH);
                    const int yc = min(max(yi, 0), BH - 1);
                    const int xc = min(max(xi, 0), BW - 1);
                    float4 v = *(const float4*)(xb + ((size_t)yc * BW + xc) * NC + c4);
                    const float f = valid ? 1.f : 0.f;
                    v.x *= f; v.y *= f; v.z *= f; v.w *= f;
                    return v;
                };
                const float4 v00 = pix(y0i, x0i);
                const float4 v01 = pix(y0i, x0i + 1);
                const float4 v10 = pix(y0i + 1, x0i);
                const float4 v11 = pix(y0i + 1, x0i + 1);
                const float owx = 1.f - wxf, owy = 1.f - wyf;
                nfloat4 rr;
                rr.x = (v00.x * owx + v01.x * wxf) * owy + (v10.x * owx + v11.x * wxf) * wyf;
                rr.y = (v00.y * owx + v01.y * wxf) * owy + (v10.y * owx + v11.y * wxf) * wyf;
                rr.z = (v00.z * owx + v01.z * wxf) * owy + (v10.z * owx + v11.z * wxf) * wyf;
                rr.w = (v00.w * owx + v01.w * wxf) * owy + (v10.w * owx + v11.w * wxf) * wyf;
                __builtin_nontemporal_store(rr, (nfloat4*)(ob + (size_t)j * 4));
            }
            if (wv == 0 && lane == 0)   // progress signal (back-pressure heuristic)
                __hip_atomic_fetch_add(&rotc[b], 1u, __ATOMIC_RELAXED, AGENT);
        }
    }
}

// ============================ fallback (R7 proven path) ======================
__global__ __launch_bounds__(256) void k_reduce(const float* __restrict__ x,
                                                const float* __restrict__ Wm,
                                                float* __restrict__ partial) {
    const int b = blockIdx.y, blk = blockIdx.x;
    const int tid = blk * 256 + threadIdx.x;
    const int tpb = RB * 256;
    const int cb = (tid * 4) & (NC - 1);
    const float w0 = Wm[cb], w1 = Wm[cb + 1], w2 = Wm[cb + 2], w3 = Wm[cb + 3];
    const float4* xb = (const float4*)(x + (size_t)b * BH * BW * NC);
    const int n4 = BH * BW * NC / 4;
    float s0 = 0.f, s1 = 0.f;
    for (int i = tid; i < n4; i += 2 * tpb) {
        float4 v0 = xb[i], v1 = xb[i + tpb];
        s0 += v0.x * w0 + v0.y * w1 + v0.z * w2 + v0.w * w3;
        s1 += v1.x * w0 + v1.y * w1 + v1.z * w2 + v1.w * w3;
    }
    float s = s0 + s1;
    for (int off = 32; off; off >>= 1) s += __shfl_down(s, off, 64);
    __shared__ float red[4];
    const int lane = threadIdx.x & 63, wv = threadIdx.x >> 6;
    if (lane == 0) red[wv] = s;
    __syncthreads();
    if (threadIdx.x == 0) partial[b * RB + blk] = red[0] + red[1] + red[2] + red[3];
}

__global__ void k_angle(const float* __restrict__ partial,
                        const float* __restrict__ bias,
                        float4* __restrict__ params) {
    const int b = threadIdx.x;
    if (b >= NB) return;
    float s = 0.f;
    for (int i = 0; i < RB; ++i) s += partial[b * RB + i];
    const float pi = 3.14159265358979323846f;
    float angle = tanhf(s * (1.f / (BH * BW)) + bias[0]) * pi;
    angle = fminf(fmaxf(angle, -pi), pi);
    const float cc = cosf(angle), ss = sinf(angle);
    const float w1 = (float)(BW - 1), h1 = (float)(BH - 1);
    params[b] = make_float4(cc, ss, (w1 - (cc * w1 - ss * h1)) * 0.5f,
                            (h1 - (ss * w1 + cc * h1)) * 0.5f);
}

__global__ __launch_bounds__(256) void k_rotate(const float* __restrict__ x,
                                                const float4* __restrict__ params,
                                                float* __restrict__ out) {
    const int gid = blockIdx.x * 256 + threadIdx.x;
    const int c4 = (gid & 7) * 4;
    const int pid = gid >> 3;
    const int b = pid >> 16, p = pid & 65535;
    const int yo = p >> 8, xo = p & 255;
    const float4 prm = params[b];
    const float cc = prm.x, sn = prm.y, xof = prm.z, yof = prm.w;
    const float fx = (float)xo, fy = (float)yo;
    const float in_x = cc * fx - sn * fy + xof;
    const float in_y = sn * fx + cc * fy + yof;
    const float x0 = floorf(in_x), y0 = floorf(in_y);
    const float wxf = in_x - x0, wyf = in_y - y0;
    const int x0i = (int)x0, y0i = (int)y0;
    const float* xb = x + (size_t)b * (BH * BW * NC);
    auto pix = [&](int yi, int xi) -> float4 {
        const bool valid = (xi >= 0) & (xi < BW) & (yi >= 0) & (yi < BH);
        const int yc = min(max(yi, 0), BH - 1), xc = min(max(xi, 0), BW - 1);
        float4 v = *(const float4*)(xb + ((size_t)yc * BW + xc) * NC + c4);
        const float f = valid ? 1.f : 0.f;
        v.x *= f; v.y *= f; v.z *= f; v.w *= f;
        return v;
    };
    const float4 v00 = pix(y0i, x0i), v01 = pix(y0i, x0i + 1);
    const float4 v10 = pix(y0i + 1, x0i), v11 = pix(y0i + 1, x0i + 1);
    const float owx = 1.f - wxf, owy = 1.f - wyf;
    nfloat4 r;
    r.x = (v00.x * owx + v01.x * wxf) * owy + (v10.x * owx + v11.x * wxf) * wyf;
    r.y = (v00.y * owx + v01.y * wxf) * owy + (v10.y * owx + v11.y * wxf) * wyf;
    r.z = (v00.z * owx + v01.z * wxf) * owy + (v10.z * owx + v11.z * wxf) * wyf;
    r.w = (v00.w * owx + v01.w * wxf) * owy + (v10.w * owx + v11.w * wxf) * wyf;
    __builtin_nontemporal_store(r, (nfloat4*)(out + (size_t)gid * 4));
}

static void launch_fallback(const float* x, const float* Wm, const float* bias,
                            float* out, char* ws, hipStream_t stream) {
    float*  partial = (float*)ws;
    float4* params  = (float4*)(ws + NB * RB * sizeof(float));
    dim3 g1(RB, NB);
    k_reduce<<<g1, 256, 0, stream>>>(x, Wm, partial);
    k_angle<<<1, 64, 0, stream>>>(partial, bias, params);
    k_rotate<<<NB * BH * BW * NC / 4 / 256, 256, 0, stream>>>(x, params, out);
}

// ================================ launcher ==================================
extern "C" void kernel_launch(void* const* d_in, const int* in_sizes, int n_in,
                              void* d_out, int out_size, void* d_ws, size_t ws_size,
                              hipStream_t stream) {
    const float* x    = (const float*)d_in[0];
    const float* Wm   = (const float*)d_in[1];
    const float* bias = (const float*)d_in[2];
    float* out = (float*)d_out;
    char* ws = (char*)d_ws;

    const size_t PART = (size_t)NB * NRED * sizeof(float);   // 128 KiB
    const size_t OFF_CNT1 = PART;                            // 4 KiB  [NB][32]
    const size_t OFF_CNT2 = OFF_CNT1 + NB * 32 * 4;          // 128 B
    const size_t OFF_ROTC = OFF_CNT2 + NB * 4;               // 128 B
    const size_t OFF_MASK = OFF_ROTC + NB * 4;               // 64 B
    const size_t OFF_PRM  = OFF_MASK + 64;                   // 512 B
    const size_t TOTAL    = OFF_PRM + NB * 4 * sizeof(float);

    if (ws_size >= TOTAL + 1024) {
        float*    partial = (float*)ws;
        unsigned* cnt1    = (unsigned*)(ws + OFF_CNT1);
        unsigned* cnt2    = (unsigned*)(ws + OFF_CNT2);
        unsigned* rotc    = (unsigned*)(ws + OFF_ROTC);
        unsigned* mask    = (unsigned*)(ws + OFF_MASK);
        float*    params  = (float*)(ws + OFF_PRM);
        if (hipMemsetAsync(ws + OFF_CNT1, 0, OFF_PRM - OFF_CNT1, stream) == hipSuccess) {
            void* args[] = { (void*)&x, (void*)&Wm, (void*)&bias, (void*)&out,
                             (void*)&partial, (void*)&cnt1, (void*)&cnt2,
                             (void*)&rotc, (void*)&mask, (void*)&params };
            hipError_t err = hipLaunchCooperativeKernel((const void*)k_fused,
                                                        dim3(NTOT), dim3(TPB),
                                                        args, 0, stream);
            if (err == hipSuccess) return;          // fused path launched
        }
    }
    launch_fallback(x, Wm, bias, out, ws, stream);  // proven 130 µs path
}

// Round 12
// 138.174 us; speedup vs baseline: 10.7778x; 10.7778x over previous
//
#include <hip/hip_runtime.h>
#include <math.h>

#define BH 256
#define BW 256
#define NB 32
#define NC 32
#define RB 64   // reduction blocks per batch

typedef float nfloat4 __attribute__((ext_vector_type(4)));
#define AGENT __HIP_MEMORY_SCOPE_AGENT

// ---- Kernel 1: per-batch weighted sum + inline last-arrival angle finalize.
// Each block writes its partial (relaxed agent atomic -> L3), drains vmcnt,
// bumps the batch counter; the 64th arrival finalizes: sums the 64 partials
// in fixed order (deterministic), computes rotation params, stores them.
// NO block ever waits -> no co-residency requirement, regular launch.
// (Fusion post-mortem R8-R11: grid-wide sync costs ~11us/event on gfx950 vs
// ~18us total cache savings -> producer/consumer fusion is net-negative.)
__global__ __launch_bounds__(256) void k_reduce_fin(
    const float* __restrict__ x, const float* __restrict__ Wm,
    const float* __restrict__ bias,
    float* __restrict__ partial,          // [NB][RB]
    unsigned* __restrict__ cnt,           // [NB]
    float* __restrict__ params)           // [NB][4] = cc, sn, xoff, yoff
{
    const int b   = blockIdx.y;
    const int blk = blockIdx.x;
    const int tid = blk * 256 + threadIdx.x;            // 0..16383 within batch
    const int tpb = RB * 256;                           // 16384
    const int cb = (tid * 4) & (NC - 1);
    const float w0 = Wm[cb], w1 = Wm[cb + 1], w2 = Wm[cb + 2], w3 = Wm[cb + 3];

    const float4* xb = (const float4*)(x + (size_t)b * BH * BW * NC);
    const int n4 = BH * BW * NC / 4;                    // 524288
    float s0 = 0.f, s1 = 0.f;
    for (int i = tid; i < n4; i += 2 * tpb) {
        float4 v0 = xb[i];
        float4 v1 = xb[i + tpb];
        s0 += v0.x * w0 + v0.y * w1 + v0.z * w2 + v0.w * w3;
        s1 += v1.x * w0 + v1.y * w1 + v1.z * w2 + v1.w * w3;
    }
    float s = s0 + s1;
    #pragma unroll
    for (int off = 32; off; off >>= 1) s += __shfl_down(s, off, 64);
    __shared__ float red[4];
    const int lane = threadIdx.x & 63, wv = threadIdx.x >> 6;
    if (lane == 0) red[wv] = s;
    __syncthreads();

    if (wv == 0) {
        if (lane == 0)
            __hip_atomic_store(&partial[b * RB + blk],
                               red[0] + red[1] + red[2] + red[3],
                               __ATOMIC_RELAXED, AGENT);
        asm volatile("s_waitcnt vmcnt(0)" ::: "memory");   // partial at L3
        int last = 0;
        if (lane == 0) {
            const unsigned old = __hip_atomic_fetch_add(&cnt[b], 1u,
                                                        __ATOMIC_RELAXED, AGENT);
            last = (old == RB - 1);
        }
        last = __shfl(last, 0, 64);
        if (last) {   // 64th arrival: finalize batch b (fixed order, no waiting)
            float q = __hip_atomic_load(&partial[b * RB + lane],
                                        __ATOMIC_RELAXED, AGENT);
            #pragma unroll
            for (int off = 32; off; off >>= 1) q += __shfl_down(q, off, 64);
            if (lane == 0) {
                const float pi = 3.14159265358979323846f;
                float angle = tanhf(q * (1.f / (BH * BW)) + bias[0]) * pi;
                angle = fminf(fmaxf(angle, -pi), pi);
                const float c_ = cosf(angle), s_ = sinf(angle);
                const float w1f = (float)(BW - 1), h1f = (float)(BH - 1);
                __hip_atomic_store(&params[b * 4 + 0], c_, __ATOMIC_RELAXED, AGENT);
                __hip_atomic_store(&params[b * 4 + 1], s_, __ATOMIC_RELAXED, AGENT);
                __hip_atomic_store(&params[b * 4 + 2],
                                   (w1f - (c_ * w1f - s_ * h1f)) * 0.5f,
                                   __ATOMIC_RELAXED, AGENT);
                __hip_atomic_store(&params[b * 4 + 3],
                                   (h1f - (s_ * w1f + c_ * h1f)) * 0.5f,
                                   __ATOMIC_RELAXED, AGENT);
            }
        }
    }
}

// ---- Kernel 2: bilinear rotate, one thread per (pixel, 4 channels).
// NT stores keep the 256 MB of output writes from evicting x (R2->R3: -25us).
__global__ __launch_bounds__(256) void k_rotate(const float* __restrict__ x,
                                                const float* __restrict__ params,
                                                float* __restrict__ out) {
    const int gid = blockIdx.x * 256 + threadIdx.x;     // 0 .. 16,777,215
    const int c4  = (gid & 7) * 4;
    const int pid = gid >> 3;
    const int b   = pid >> 16;
    const int p   = pid & 65535;
    const int yo  = p >> 8;
    const int xo  = p & 255;

    const float4 prm = *(const float4*)(params + b * 4);
    const float cc = prm.x, sn = prm.y, xoff = prm.z, yoff = prm.w;
    const float fx = (float)xo, fy = (float)yo;
    const float in_x = cc * fx - sn * fy + xoff;
    const float in_y = sn * fx + cc * fy + yoff;
    const float x0 = floorf(in_x), y0 = floorf(in_y);
    const float wx = in_x - x0, wy = in_y - y0;
    const int x0i = (int)x0, y0i = (int)y0;

    const float* xb = x + (size_t)b * (BH * BW * NC);

    auto pix = [&](int yi, int xi) -> float4 {
        const bool valid = (xi >= 0) & (xi < BW) & (yi >= 0) & (yi < BH);
        const int yc = min(max(yi, 0), BH - 1);
        const int xc = min(max(xi, 0), BW - 1);
        float4 v = *(const float4*)(xb + ((size_t)yc * BW + xc) * NC + c4);
        const float f = valid ? 1.f : 0.f;
        v.x *= f; v.y *= f; v.z *= f; v.w *= f;
        return v;
    };

    const float4 v00 = pix(y0i, x0i);
    const float4 v01 = pix(y0i, x0i + 1);
    const float4 v10 = pix(y0i + 1, x0i);
    const float4 v11 = pix(y0i + 1, x0i + 1);

    const float owx = 1.f - wx, owy = 1.f - wy;
    nfloat4 r;
    r.x = (v00.x * owx + v01.x * wx) * owy + (v10.x * owx + v11.x * wx) * wy;
    r.y = (v00.y * owx + v01.y * wx) * owy + (v10.y * owx + v11.y * wx) * wy;
    r.z = (v00.z * owx + v01.z * wx) * owy + (v10.z * owx + v11.z * wx) * wy;
    r.w = (v00.w * owx + v01.w * wx) * owy + (v10.w * owx + v11.w * wx) * wy;

    __builtin_nontemporal_store(r, (nfloat4*)(out + (size_t)gid * 4));
}

extern "C" void kernel_launch(void* const* d_in, const int* in_sizes, int n_in,
                              void* d_out, int out_size, void* d_ws, size_t ws_size,
                              hipStream_t stream) {
    const float* x    = (const float*)d_in[0];
    const float* Wm   = (const float*)d_in[1];
    const float* bias = (const float*)d_in[2];
    float* out = (float*)d_out;
    char* ws = (char*)d_ws;

    float*    partial = (float*)ws;                     // NB*RB floats = 8 KiB
    unsigned* cnt     = (unsigned*)(ws + NB * RB * sizeof(float));   // 128 B
    float*    params  = (float*)(ws + NB * RB * sizeof(float) + 128); // 512 B

    hipMemsetAsync(cnt, 0, NB * sizeof(unsigned), stream);

    dim3 g1(RB, NB);
    k_reduce_fin<<<g1, 256, 0, stream>>>(x, Wm, bias, partial, cnt, params);

    const int total4 = NB * BH * BW * NC / 4;           // 16,777,216
    k_rotate<<<total4 / 256, 256, 0, stream>>>(x, params, out);
}

// Round 13
// 130.450 us; speedup vs baseline: 11.4159x; 1.0592x over previous
//
#include <hip/hip_runtime.h>
#include <math.h>

#define BH 256
#define BW 256
#define NB 32
#define NC 32
#define RB 64   // reduction blocks per batch

typedef float nfloat4 __attribute__((ext_vector_type(4)));  // native vec for nontemporal builtin

// ---------------- Kernel 1: per-batch weighted sum  S[b] = sum x[b,h,w,c]*Wm[c]
__global__ __launch_bounds__(256) void k_reduce(const float* __restrict__ x,
                                                const float* __restrict__ Wm,
                                                float* __restrict__ partial) {
    const int b   = blockIdx.y;
    const int blk = blockIdx.x;
    const int tid = blk * 256 + threadIdx.x;            // 0..16383 within batch
    const int tpb = RB * 256;                           // 16384
    const int cb = (tid * 4) & (NC - 1);
    const float w0 = Wm[cb + 0], w1 = Wm[cb + 1], w2 = Wm[cb + 2], w3 = Wm[cb + 3];

    const float4* xb = (const float4*)(x + (size_t)b * BH * BW * NC);
    const int n4 = BH * BW * NC / 4;                    // 524288
    float s0 = 0.f, s1 = 0.f;
    for (int i = n4 - 2 * tpb + tid; i >= 0; i -= 2 * tpb) {
        float4 v0 = xb[i + tpb];
        float4 v1 = xb[i];
        s0 += v0.x * w0 + v0.y * w1 + v0.z * w2 + v0.w * w3;
        s1 += v1.x * w0 + v1.y * w1 + v1.z * w2 + v1.w * w3;
    }
    float s = s0 + s1;
    for (int off = 32; off; off >>= 1) s += __shfl_down(s, off, 64);
    __shared__ float red[4];
    const int lane = threadIdx.x & 63, wv = threadIdx.x >> 6;
    if (lane == 0) red[wv] = s;
    __syncthreads();
    if (threadIdx.x == 0)
        partial[b * RB + blk] = red[0] + red[1] + red[2] + red[3];
}

// ---------------- Kernel 2: finish reduction, compute per-batch rotation params
__global__ void k_angle(const float* __restrict__ partial,
                        const float* __restrict__ bias,
                        float4* __restrict__ params) {
    const int b = threadIdx.x;
    if (b >= NB) return;
    float s = 0.f;
    for (int i = 0; i < RB; ++i) s += partial[b * RB + i];
    const float pi = 3.14159265358979323846f;
    float angle = tanhf(s * (1.f / (BH * BW)) + bias[0]) * pi;
    angle = fminf(fmaxf(angle, -pi), pi);
    const float cc = cosf(angle), ss = sinf(angle);
    const float w1 = (float)(BW - 1), h1 = (float)(BH - 1);
    const float xoff = (w1 - (cc * w1 - ss * h1)) * 0.5f;
    const float yoff = (h1 - (ss * w1 + cc * h1)) * 0.5f;
    params[b] = make_float4(cc, ss, xoff, yoff);
}

// ---------------- Kernel 3: bilinear rotate, one thread per (pixel, 4 channels)
// NT stores: 256 MB of output writes must not evict x from L3 (R2->R3: -25us).
__global__ __launch_bounds__(256) void k_rotate(const float* __restrict__ x,
                                                const float4* __restrict__ params,
                                                float* __restrict__ out) {
    const int gid = blockIdx.x * 256 + threadIdx.x;     // 0 .. 16,777,215
    const int c4  = (gid & 7) * 4;
    const int pid = gid >> 3;
    const int b   = pid >> 16;
    const int p   = pid & 65535;
    const int yo  = p >> 8;
    const int xo  = p & 255;

    const float4 prm = params[b];
    const float cc = prm.x, sn = prm.y, xoff = prm.z, yoff = prm.w;
    const float fx = (float)xo, fy = (float)yo;
    const float in_x = cc * fx - sn * fy + xoff;
    const float in_y = sn * fx + cc * fy + yoff;
    const float x0 = floorf(in_x), y0 = floorf(in_y);
    const float wx = in_x - x0, wy = in_y - y0;
    const int x0i = (int)x0, y0i = (int)y0;

    const float* xb = x + (size_t)b * (BH * BW * NC);

    auto pix = [&](int yi, int xi) -> float4 {
        const bool valid = (xi >= 0) & (xi < BW) & (yi >= 0) & (yi < BH);
        const int yc = min(max(yi, 0), BH - 1);
        const int xc = min(max(xi, 0), BW - 1);
        float4 v = *(const float4*)(xb + ((size_t)yc * BW + xc) * NC + c4);
        const float f = valid ? 1.f : 0.f;
        v.x *= f; v.y *= f; v.z *= f; v.w *= f;
        return v;
    };

    const float4 v00 = pix(y0i, x0i);
    const float4 v01 = pix(y0i, x0i + 1);
    const float4 v10 = pix(y0i + 1, x0i);
    const float4 v11 = pix(y0i + 1, x0i + 1);

    const float owx = 1.f - wx, owy = 1.f - wy;
    nfloat4 r;
    r.x = (v00.x * owx + v01.x * wx) * owy + (v10.x * owx + v11.x * wx) * wy;
    r.y = (v00.y * owx + v01.y * wx) * owy + (v10.y * owx + v11.y * wx) * wy;
    r.z = (v00.z * owx + v01.z * wx) * owy + (v10.z * owx + v11.z * wx) * wy;
    r.w = (v00.w * owx + v01.w * wx) * owy + (v10.w * owx + v11.w * wx) * wy;

    __builtin_nontemporal_store(r, (nfloat4*)(out + (size_t)gid * 4));
}

extern "C" void kernel_launch(void* const* d_in, const int* in_sizes, int n_in,
                              void* d_out, int out_size, void* d_ws, size_t ws_size,
                              hipStream_t stream) {
    const float* x    = (const float*)d_in[0];
    const float* Wm   = (const float*)d_in[1];
    const float* bias = (const float*)d_in[2];
    float* out = (float*)d_out;

    float*  partial = (float*)d_ws;                         // NB*RB floats = 8 KiB
    float4* params  = (float4*)((char*)d_ws + NB * RB * sizeof(float));

    dim3 g1(RB, NB);
    k_reduce<<<g1, 256, 0, stream>>>(x, Wm, partial);
    k_angle<<<1, 64, 0, stream>>>(partial, bias, params);

    const int total4 = NB * BH * BW * NC / 4;               // 16,777,216
    k_rotate<<<total4 / 256, 256, 0, stream>>>(x, params, out);
}